// Round 2
// baseline (103.286 us; speedup 1.0000x reference)
//
#include <hip/hip_runtime.h>
#include <hip/hip_bf16.h>

#define NUP 8
#define NDOWN 8
#define NMO 32
#define NCONF 64
#define NBATCH 16384
#define BPB 4   // batches per 256-thread block (one wave = one batch's 64 confs)

// 8x8 determinant via fully-unrolled Gaussian elimination with partial
// pivoting. All indices compile-time after unrolling -> stays in VGPRs
// (runtime-indexed register arrays would go to scratch, rule #20).
//
// Sign-free pivoting: instead of {swap rows k,i; sign = -sign}, do the
// det-preserving pseudo-swap {row_k <- row_i; row_i <- -row_k}:
//   det(swap) = -det;  negating one row flips it back -> det unchanged.
// The negation folds into the v_cndmask source modifier; the |.| pivot
// compares are sign-blind, so later pivot searches are unaffected.
__device__ __forceinline__ float det8(const float* __restrict__ base,
                                      int4 ca, int4 cb) {
    float m[8][8];
    const int cols[8] = {ca.x, ca.y, ca.z, ca.w, cb.x, cb.y, cb.z, cb.w};
#pragma unroll
    for (int j = 0; j < 8; ++j) {
#pragma unroll
        for (int i = 0; i < 8; ++i) {
            // addr = base + cols[j]*4 + i*128 -> ds_read_b32 with offset:i*128
            m[i][j] = base[i * NMO + cols[j]];
        }
    }

    float det = 1.0f;
#pragma unroll
    for (int k = 0; k < 8; ++k) {
        // Static compare-and-pseudo-swap chain: after it, row k holds the
        // max-|.| pivot among rows k..7 (same row choice as LAPACK).
#pragma unroll
        for (int i = k + 1; i < 8; ++i) {
            bool sw = fabsf(m[i][k]) > fabsf(m[k][k]);  // abs folds into v_cmp
#pragma unroll
            for (int j = k; j < 8; ++j) {
                float a = m[k][j], b = m[i][j];
                m[k][j] = sw ? b : a;
                m[i][j] = sw ? -a : b;   // neg folds into cndmask src modifier
            }
        }
        det *= m[k][k];
        if (k < 7) {
            // v_rcp_f32 (2^-22 rel err) instead of ~10-instr IEEE divide:
            // det error stays ~1e-6, same order as fp32 LU noise.
            float r = __builtin_amdgcn_rcpf(m[k][k]);
#pragma unroll
            for (int i = k + 1; i < 8; ++i) {
                float f = m[i][k] * r;
#pragma unroll
                for (int j = k + 1; j < 8; ++j) {
                    m[i][j] = fmaf(-f, m[k][j], m[i][j]);
                }
            }
        }
    }
    return det;
}

__global__ __launch_bounds__(256) void slater_kernel(
        const float* __restrict__ inp,     // [NBATCH][16][NMO] f32
        const int*   __restrict__ cup,     // [NCONF][NUP]
        const int*   __restrict__ cdown,   // [NCONF][NDOWN]
        float*       __restrict__ out)     // [NBATCH][NCONF]
{
    __shared__ float lds[BPB * 16 * NMO];  // 4 batches x 2KB = 8KB

    const int tid    = threadIdx.x;
    const int batch0 = blockIdx.x * BPB;

    // Cooperative stage: 4 batches x 512 f32 = 512 float4, 2 per thread,
    // fully coalesced (1KB per instruction per wave).
    {
        const float4* src = reinterpret_cast<const float4*>(inp + (size_t)batch0 * 16 * NMO);
        float4* dst = reinterpret_cast<float4*>(lds);
        dst[tid]       = src[tid];
        dst[tid + 256] = src[tid + 256];
    }
    __syncthreads();

    const int conf = tid & 63;   // wave = all 64 confs of one batch
    const int bl   = tid >> 6;

    const float* base_up = lds + bl * 16 * NMO;
    const float* base_dn = base_up + NUP * NMO;

    // Index rows: 8 contiguous ints each; same 2KB table for every block -> L2-hot.
    const int4 u0 = reinterpret_cast<const int4*>(cup   + conf * NUP)[0];
    const int4 u1 = reinterpret_cast<const int4*>(cup   + conf * NUP)[1];
    const int4 d0 = reinterpret_cast<const int4*>(cdown + conf * NDOWN)[0];
    const int4 d1 = reinterpret_cast<const int4*>(cdown + conf * NDOWN)[1];

    const float det_up = det8(base_up, u0, u1);
    const float det_dn = det8(base_dn, d0, d1);

    // Coalesced: 64 consecutive floats per wave.
    out[(size_t)(batch0 + bl) * NCONF + conf] = det_up * det_dn;
}

extern "C" void kernel_launch(void* const* d_in, const int* in_sizes, int n_in,
                              void* d_out, int out_size, void* d_ws, size_t ws_size,
                              hipStream_t stream) {
    const float* inp   = reinterpret_cast<const float*>(d_in[0]);
    const int*   cup   = reinterpret_cast<const int*>(d_in[1]);
    const int*   cdown = reinterpret_cast<const int*>(d_in[2]);
    float*       out   = reinterpret_cast<float*>(d_out);

    dim3 grid(NBATCH / BPB);   // 4096 blocks
    dim3 block(256);
    slater_kernel<<<grid, block, 0, stream>>>(inp, cup, cdown, out);
}